// Round 8
// baseline (288.007 us; speedup 1.0000x reference)
//
#include <hip/hip_runtime.h>
#include <hip/hip_bf16.h>
#include <stdint.h>

// Problem constants
#define NB 8
#define NL 1024
#define NC 512
#define NH 8
#define ND 64

typedef __attribute__((ext_vector_type(8))) short short8;
typedef __attribute__((ext_vector_type(4))) float f32x4;
typedef unsigned long long u64;

__device__ __forceinline__ short f2bf(float f) {
  union { float f; uint32_t u; } v; v.f = f;
  uint32_t r = v.u + 0x7FFFu + ((v.u >> 16) & 1u);  // RNE
  return (short)(r >> 16);
}

#if __has_builtin(__builtin_amdgcn_exp2f)
#define EXP2(x) __builtin_amdgcn_exp2f(x)
#else
#define EXP2(x) exp2f(x)
#endif

#define MFMA16(a, b, c) __builtin_amdgcn_mfma_f32_16x16x32_bf16((a), (b), (c), 0, 0, 0)

// ---------------------------------------------------------------------------
// K0: pack adj_local rows (row 0 / col 0 zeroed per has_cls) AND dist>0 rows
// into 16xu64 bitmasks per row.
// ---------------------------------------------------------------------------
__global__ __launch_bounds__(256) void pack_k(const float* __restrict__ adj,
                                              const float* __restrict__ dist,
                                              u64* __restrict__ padj,
                                              u64* __restrict__ pdist) {
  int row = blockIdx.x;             // b*NL + i
  int i = row & (NL - 1);
  int wv = threadIdx.x >> 6, lane = threadIdx.x & 63;
  const float* asrc = adj + (size_t)row * NL;
  const float* dsrc = dist + (size_t)row * NL;
  #pragma unroll
  for (int it = 0; it < 4; it++) {
    int j = wv * 256 + it * 64 + lane;
    float a = asrc[j];
    float d = dsrc[j];
    u64 am = __ballot((a != 0.0f) && (i != 0) && (j != 0));
    u64 dm = __ballot(d > 0.0f);
    if (lane == 0) {
      padj[(size_t)row * 16 + wv * 4 + it] = am;
      pdist[(size_t)row * 16 + wv * 4 + it] = dm;
    }
  }
}

// ---------------------------------------------------------------------------
// K2: 5-bit bias masks per (b,i,j) from packed bitmasks.
// ---------------------------------------------------------------------------
__global__ __launch_bounds__(256) void bits_k(const u64* __restrict__ padj,
                                              const u64* __restrict__ pdist,
                                              unsigned char* __restrict__ bits) {
  __shared__ u64 Pi[64][17], Pj[64][17];
  __shared__ u64 DiW[64], DjW[64];
  int b = blockIdx.z, i0 = blockIdx.y * 64, j0 = blockIdx.x * 64;
  int t = threadIdx.x;
  int jw = j0 >> 6, iw = i0 >> 6;
  const u64* pa = padj + (size_t)b * NL * 16;
  const u64* pd = pdist + (size_t)b * NL * 16;
  #pragma unroll
  for (int s = 0; s < 4; s++) {
    int idx = s * 256 + t; int r = idx >> 4, w = idx & 15;
    Pi[r][w] = pa[(size_t)(i0 + r) * 16 + w];
    Pj[r][w] = pa[(size_t)(j0 + r) * 16 + w];
  }
  if (t < 64) DiW[t] = pd[(size_t)(i0 + t) * 16 + jw];
  else if (t < 128) DjW[t - 64] = pd[(size_t)(j0 + t - 64) * 16 + iw];
  __syncthreads();
  const size_t base = (size_t)b * NL * NL;
  int jj0 = (t & 15) * 4;
  #pragma unroll
  for (int s = 0; s < 4; s++) {
    int ii = (t >> 4) + s * 16;
    u64 fwdw = Pi[ii][jw];
    u64 dfw = DiW[ii];
    uint32_t acc = 0;
    #pragma unroll
    for (int q = 0; q < 4; q++) {
      int jj = jj0 + q;
      unsigned v = 0;
      v |= (unsigned)((fwdw >> jj) & 1);
      v |= (unsigned)((Pj[jj][iw] >> ii) & 1) << 1;
      v |= (unsigned)((dfw >> jj) & 1) << 2;
      v |= (unsigned)((DjW[jj] >> ii) & 1) << 3;
      #pragma unroll 1
      for (int w = 0; w < 16; w++) {
        if (Pi[ii][w] & Pj[jj][w]) { v |= 16; break; }
      }
      acc |= v << (8 * q);
    }
    *(uint32_t*)&bits[base + (size_t)(i0 + ii) * NL + j0 + jj0] = acc;
  }
}

// ---------------------------------------------------------------------------
// K0b: convert+transpose a weight matrix: w[K][N] f32 -> wt[N][K] bf16.
// ---------------------------------------------------------------------------
__global__ __launch_bounds__(256) void wcvt_k(const float* __restrict__ w,
                                              unsigned short* __restrict__ wt,
                                              int Ndim) {
  __shared__ short T[64][68];
  int k0 = blockIdx.y * 64, n0 = blockIdx.x * 64;
  int t = threadIdx.x;
  {
    int r = t >> 2, c0 = (t & 3) * 16;
    const float* src = w + (size_t)(k0 + r) * Ndim + n0 + c0;
    float4 a0 = *(const float4*)src;
    float4 a1 = *(const float4*)(src + 4);
    float4 a2 = *(const float4*)(src + 8);
    float4 a3 = *(const float4*)(src + 12);
    short8 s0, s1;
    s0[0] = f2bf(a0.x); s0[1] = f2bf(a0.y); s0[2] = f2bf(a0.z); s0[3] = f2bf(a0.w);
    s0[4] = f2bf(a1.x); s0[5] = f2bf(a1.y); s0[6] = f2bf(a1.z); s0[7] = f2bf(a1.w);
    s1[0] = f2bf(a2.x); s1[1] = f2bf(a2.y); s1[2] = f2bf(a2.z); s1[3] = f2bf(a2.w);
    s1[4] = f2bf(a3.x); s1[5] = f2bf(a3.y); s1[6] = f2bf(a3.z); s1[7] = f2bf(a3.w);
    *(short8*)&T[r][c0]     = s0;
    *(short8*)&T[r][c0 + 8] = s1;
  }
  __syncthreads();
  #pragma unroll
  for (int it = 0; it < 2; it++) {
    int nn = (t >> 3) + it * 32, kc = (t & 7) * 8;
    short8 v;
    #pragma unroll
    for (int j = 0; j < 8; j++) v[j] = T[kc + j][nn];
    *(short8*)(wt + (size_t)(n0 + nn) * NC + k0 + kc) = v;
  }
}

// ---------------------------------------------------------------------------
// K1: qkv = x @ w_qkv  (bf16 MFMA, f32 accum), scatter to q/k/v [B,H,L,D] bf16
// ---------------------------------------------------------------------------
__global__ __launch_bounds__(256) void qkv_gemm_k(const float* __restrict__ x,
                                                  const unsigned short* __restrict__ wqT,
                                                  unsigned short* __restrict__ qb,
                                                  unsigned short* __restrict__ kb,
                                                  unsigned short* __restrict__ vb) {
  __shared__ short Al[64][40];   // [m][k]
  __shared__ short Bl[64][40];   // [n][k]
  int t = threadIdx.x;
  int wv = t >> 6, lane = t & 63, lg = lane >> 4, lm = lane & 15;
  int wr = wv >> 1, wc = wv & 1;
  int M0 = blockIdx.y * 64, N0 = blockIdx.x * 64;
  f32x4 zero4 = {0.f, 0.f, 0.f, 0.f};
  f32x4 acc[2][2] = {{zero4, zero4}, {zero4, zero4}};
  for (int k0 = 0; k0 < NC; k0 += 32) {
    {
      int row = t >> 2, cc = (t & 3) * 8;
      const float* src = x + (size_t)(M0 + row) * NC + k0 + cc;
      float4 v0 = *(const float4*)src;
      float4 v1 = *(const float4*)(src + 4);
      short8 s8;
      s8[0] = f2bf(v0.x); s8[1] = f2bf(v0.y); s8[2] = f2bf(v0.z); s8[3] = f2bf(v0.w);
      s8[4] = f2bf(v1.x); s8[5] = f2bf(v1.y); s8[6] = f2bf(v1.z); s8[7] = f2bf(v1.w);
      *(short8*)&Al[row][cc] = s8;
    }
    {
      int n = t >> 2, kk = (t & 3) * 8;
      *(short8*)&Bl[n][kk] =
          *(const short8*)(wqT + (size_t)(N0 + n) * NC + k0 + kk);
    }
    __syncthreads();
    short8 af[2], bfr[2];
    af[0] = *(short8*)&Al[wr * 32 + lm][lg * 8];
    af[1] = *(short8*)&Al[wr * 32 + 16 + lm][lg * 8];
    bfr[0] = *(short8*)&Bl[wc * 32 + lm][lg * 8];
    bfr[1] = *(short8*)&Bl[wc * 32 + 16 + lm][lg * 8];
    #pragma unroll
    for (int mi = 0; mi < 2; mi++)
      #pragma unroll
      for (int ni = 0; ni < 2; ni++)
        acc[mi][ni] = MFMA16(af[mi], bfr[ni], acc[mi][ni]);
    __syncthreads();
  }
  #pragma unroll
  for (int mi = 0; mi < 2; mi++)
    #pragma unroll
    for (int ni = 0; ni < 2; ni++)
      #pragma unroll
      for (int r = 0; r < 4; r++) {
        int m = M0 + wr * 32 + mi * 16 + lg * 4 + r;
        int n = N0 + wc * 32 + ni * 16 + lm;
        int which = n >> 9, c = n & 511;
        int h = c >> 6, d = c & 63;
        int bb = m >> 10, ll = m & 1023;
        float val = acc[mi][ni][r];
        unsigned short* dst;
        if (which == 0) { dst = qb; val *= 0.125f; }
        else dst = (which == 1) ? kb : vb;
        dst[(((size_t)bb * NH + h) * NL + ll) * ND + d] = (unsigned short)f2bf(val);
      }
}

// ---------------------------------------------------------------------------
// K1b: transpose V [B,H,L,D] -> [B,H,D,L]
// ---------------------------------------------------------------------------
__global__ __launch_bounds__(256) void vt_k(const unsigned short* __restrict__ vb,
                                            unsigned short* __restrict__ vtb) {
  __shared__ short T[64][68];
  int b = blockIdx.z, h = blockIdx.y, l0 = blockIdx.x * 64;
  int t = threadIdx.x;
  const size_t bh = (size_t)b * NH + h;
  {
    int r = t >> 2, c0 = (t & 3) * 16;
    const unsigned short* src = vb + ((bh * NL) + l0 + r) * ND + c0;
    *(short8*)&T[r][c0]     = *(const short8*)src;
    *(short8*)&T[r][c0 + 8] = *(const short8*)(src + 8);
  }
  __syncthreads();
  #pragma unroll
  for (int it = 0; it < 2; it++) {
    int d = (t >> 3) + it * 32, lc = (t & 7) * 8;
    short8 v;
    #pragma unroll
    for (int j = 0; j < 8; j++) v[j] = T[lc + j][d];
    *(short8*)(vtb + (bh * ND + d) * NL + l0 + lc) = v;
  }
}

// ---------------------------------------------------------------------------
// K3: fused flash attention, fixed-shift exp2 softmax.
// Double-buffered K/V LDS (T14 async split: loads issued before compute,
// LDS writes after; 1 barrier/tile). Bias via 5x cndmask chain (no LDS lut).
// ---------------------------------------------------------------------------
__global__ __launch_bounds__(256) void attn_k(const unsigned short* __restrict__ qb,
                                              const unsigned short* __restrict__ kb,
                                              const unsigned short* __restrict__ vtb,
                                              const unsigned char* __restrict__ bits,
                                              const float* __restrict__ gamma,
                                              unsigned short* __restrict__ ao) {
  __shared__ short Kl[2][64][72];   // [buf][kv][d]
  __shared__ short Vt[2][64][72];   // [buf][d][kv]
  __shared__ short Pl[64][68];      // [q][kv] bf16 probs
  int b = blockIdx.z, h = blockIdx.y, q0 = blockIdx.x * 64;
  int t = threadIdx.x, wv = t >> 6, lane = t & 63, lg = lane >> 4, lm = lane & 15;
  const float LOG2E = 1.4426950408889634f;
  // uniform per-block gamma scalars, pre-scaled to exp2 domain
  float G0 = gamma[h * 5 + 0] * LOG2E;
  float G1 = gamma[h * 5 + 1] * LOG2E;
  float G2 = gamma[h * 5 + 2] * LOG2E;
  float G3 = gamma[h * 5 + 3] * LOG2E;
  float G4 = gamma[h * 5 + 4] * LOG2E;
  const size_t bh = ((size_t)b * NH + h) * NL;
  const size_t bhD = ((size_t)b * NH + h) * ND;
  short8 qf[2];
  {
    const unsigned short* src = qb + (bh + q0 + wv * 16 + lm) * ND + lg * 8;
    qf[0] = *(const short8*)src;
    qf[1] = *(const short8*)(src + 32);
  }
  // staging geometry: thread covers row sr, 16-elem seg scc (two b128s)
  int sr = t >> 2, scc = (t & 3) * 16;
  const unsigned short* krow = kb + (bh + sr) * ND + scc;       // + j0*ND rows
  const unsigned short* vrow = vtb + (bhD + sr) * NL + scc;     // + j0 cols
  const unsigned char* brow = bits + ((size_t)b * NL + q0 + wv * 16 + lg * 4) * NL + lm;
  // prologue: stage tile 0
  short8 kr0 = *(const short8*)(krow);
  short8 kr1 = *(const short8*)(krow + 8);
  short8 vr0 = *(const short8*)(vrow);
  short8 vr1 = *(const short8*)(vrow + 8);
  *(short8*)&Kl[0][sr][scc] = kr0;  *(short8*)&Kl[0][sr][scc + 8] = kr1;
  *(short8*)&Vt[0][sr][scc] = vr0;  *(short8*)&Vt[0][sr][scc + 8] = vr1;
  __syncthreads();
  f32x4 zero4 = {0.f, 0.f, 0.f, 0.f};
  f32x4 oacc[4] = {zero4, zero4, zero4, zero4};
  float lsum[4] = {0.f, 0.f, 0.f, 0.f};
  for (int ti = 0; ti < 16; ti++) {
    int cur = ti & 1;
    int j0 = ti * 64;
    // issue next tile's global loads early (hidden under compute)
    if (ti < 15) {
      kr0 = *(const short8*)(krow + (size_t)(j0 + 64) * ND);
      kr1 = *(const short8*)(krow + (size_t)(j0 + 64) * ND + 8);
      vr0 = *(const short8*)(vrow + j0 + 64);
      vr1 = *(const short8*)(vrow + j0 + 64 + 8);
    }
    // prefetch this tile's bias bits (consumed after QK MFMAs)
    unsigned bq[16];
    #pragma unroll
    for (int ni = 0; ni < 4; ni++)
      #pragma unroll
      for (int r = 0; r < 4; r++)
        bq[ni * 4 + r] = brow[(size_t)r * NL + j0 + ni * 16];
    // S = Q K^T
    f32x4 sf[4];
    #pragma unroll
    for (int ni = 0; ni < 4; ni++) {
      short8 b0 = *(short8*)&Kl[cur][ni * 16 + lm][lg * 8];
      short8 b1 = *(short8*)&Kl[cur][ni * 16 + lm][32 + lg * 8];
      f32x4 c = {0.f, 0.f, 0.f, 0.f};
      c = MFMA16(qf[0], b0, c);
      c = MFMA16(qf[1], b1, c);
      sf[ni] = c;
    }
    // p = exp2(s*log2e + bias - 8); bias via cndmask chain
    #pragma unroll
    for (int ni = 0; ni < 4; ni++)
      #pragma unroll
      for (int r = 0; r < 4; r++) {
        unsigned bt = bq[ni * 4 + r];
        float bias = -8.0f;
        bias += (bt & 1u) ? G0 : 0.0f;
        bias += (bt & 2u) ? G1 : 0.0f;
        bias += (bt & 4u) ? G2 : 0.0f;
        bias += (bt & 8u) ? G3 : 0.0f;
        bias += (bt & 16u) ? G4 : 0.0f;
        float p = EXP2(fmaf(sf[ni][r], LOG2E, bias));
        lsum[r] += p;
        Pl[wv * 16 + lg * 4 + r][ni * 16 + lm] = f2bf(p);
      }
    short8 pa0 = *(short8*)&Pl[wv * 16 + lm][lg * 8];
    short8 pa1 = *(short8*)&Pl[wv * 16 + lm][32 + lg * 8];
    #pragma unroll
    for (int di = 0; di < 4; di++) {
      short8 vb0 = *(short8*)&Vt[cur][di * 16 + lm][lg * 8];
      short8 vb1 = *(short8*)&Vt[cur][di * 16 + lm][32 + lg * 8];
      oacc[di] = MFMA16(pa0, vb0, oacc[di]);
      oacc[di] = MFMA16(pa1, vb1, oacc[di]);
    }
    // write next tile into alternate buffer; single barrier per tile
    if (ti < 15) {
      *(short8*)&Kl[cur ^ 1][sr][scc] = kr0;
      *(short8*)&Kl[cur ^ 1][sr][scc + 8] = kr1;
      *(short8*)&Vt[cur ^ 1][sr][scc] = vr0;
      *(short8*)&Vt[cur ^ 1][sr][scc + 8] = vr1;
      __syncthreads();
    }
  }
  // final row-sum reduce (once)
  float inv[4];
  #pragma unroll
  for (int r = 0; r < 4; r++) {
    float s = lsum[r];
    s += __shfl_xor(s, 1);
    s += __shfl_xor(s, 2);
    s += __shfl_xor(s, 4);
    s += __shfl_xor(s, 8);
    inv[r] = 1.0f / s;
  }
  #pragma unroll
  for (int di = 0; di < 4; di++)
    #pragma unroll
    for (int r = 0; r < 4; r++) {
      int qi = q0 + wv * 16 + lg * 4 + r;
      int d = di * 16 + lm;
      ao[((size_t)b * NL + qi) * NC + h * ND + d] =
          (unsigned short)f2bf(oacc[di][r] * inv[r]);
    }
}

// ---------------------------------------------------------------------------
// K4: out = attn_out @ w_proj  (bf16 MFMA, f32 out)
// ---------------------------------------------------------------------------
__global__ __launch_bounds__(256) void proj_gemm_k(const unsigned short* __restrict__ ao,
                                                   const unsigned short* __restrict__ wpT,
                                                   float* __restrict__ out) {
  __shared__ short Al[64][40];
  __shared__ short Bl[64][40];
  int t = threadIdx.x;
  int wv = t >> 6, lane = t & 63, lg = lane >> 4, lm = lane & 15;
  int wr = wv >> 1, wc = wv & 1;
  int M0 = blockIdx.y * 64, N0 = blockIdx.x * 64;
  f32x4 zero4 = {0.f, 0.f, 0.f, 0.f};
  f32x4 acc[2][2] = {{zero4, zero4}, {zero4, zero4}};
  for (int k0 = 0; k0 < NC; k0 += 32) {
    {
      int row = t >> 2, cc = (t & 3) * 8;
      *(short8*)&Al[row][cc] = *(const short8*)(ao + (size_t)(M0 + row) * NC + k0 + cc);
    }
    {
      int n = t >> 2, kk = (t & 3) * 8;
      *(short8*)&Bl[n][kk] =
          *(const short8*)(wpT + (size_t)(N0 + n) * NC + k0 + kk);
    }
    __syncthreads();
    short8 af[2], bfr[2];
    af[0] = *(short8*)&Al[wr * 32 + lm][lg * 8];
    af[1] = *(short8*)&Al[wr * 32 + 16 + lm][lg * 8];
    bfr[0] = *(short8*)&Bl[wc * 32 + lm][lg * 8];
    bfr[1] = *(short8*)&Bl[wc * 32 + 16 + lm][lg * 8];
    #pragma unroll
    for (int mi = 0; mi < 2; mi++)
      #pragma unroll
      for (int ni = 0; ni < 2; ni++)
        acc[mi][ni] = MFMA16(af[mi], bfr[ni], acc[mi][ni]);
    __syncthreads();
  }
  #pragma unroll
  for (int mi = 0; mi < 2; mi++)
    #pragma unroll
    for (int ni = 0; ni < 2; ni++)
      #pragma unroll
      for (int r = 0; r < 4; r++) {
        int m = M0 + wr * 32 + mi * 16 + lg * 4 + r;
        int n = N0 + wc * 32 + ni * 16 + lm;
        out[(size_t)m * NC + n] = acc[mi][ni][r];
      }
}

// ---------------------------------------------------------------------------
extern "C" void kernel_launch(void* const* d_in, const int* in_sizes, int n_in,
                              void* d_out, int out_size, void* d_ws, size_t ws_size,
                              hipStream_t stream) {
  (void)in_sizes; (void)n_in; (void)out_size; (void)ws_size;
  const float* x      = (const float*)d_in[0];
  const float* adj    = (const float*)d_in[1];
  const float* dist   = (const float*)d_in[2];
  const float* w_qkv  = (const float*)d_in[3];
  const float* w_proj = (const float*)d_in[4];
  const float* gamma  = (const float*)d_in[5];
  float* out = (float*)d_out;

  // workspace layout (~55 MB total)
  char* ws = (char*)d_ws;
  size_t off = 0;
  auto take = [&](size_t bytes) -> char* {
    char* p = ws + off;
    off += (bytes + 255) & ~(size_t)255;
    return p;
  };
  unsigned short* qb = (unsigned short*)take((size_t)NB * NH * NL * ND * 2);
  unsigned short* kb = (unsigned short*)take((size_t)NB * NH * NL * ND * 2);
  unsigned short* vb = (unsigned short*)take((size_t)NB * NH * NL * ND * 2);
  unsigned short* vtb = (unsigned short*)take((size_t)NB * NH * NL * ND * 2);
  u64* padj  = (u64*)take((size_t)NB * NL * 16 * 8);
  u64* pdist = (u64*)take((size_t)NB * NL * 16 * 8);
  unsigned char* bits = (unsigned char*)take((size_t)NB * NL * NL);
  unsigned short* ao = (unsigned short*)take((size_t)NB * NL * NC * 2);
  unsigned short* wqT = (unsigned short*)take((size_t)3 * NC * NC * 2);
  unsigned short* wpT = (unsigned short*)take((size_t)NC * NC * 2);

  pack_k<<<dim3(NB * NL), dim3(256), 0, stream>>>(adj, dist, padj, pdist);
  wcvt_k<<<dim3(24, 8), dim3(256), 0, stream>>>(w_qkv, wqT, 3 * NC);
  wcvt_k<<<dim3(8, 8), dim3(256), 0, stream>>>(w_proj, wpT, NC);
  qkv_gemm_k<<<dim3(24, 128), dim3(256), 0, stream>>>(x, wqT, qb, kb, vb);
  vt_k<<<dim3(16, NH, NB), dim3(256), 0, stream>>>(vb, vtb);
  bits_k<<<dim3(16, 16, NB), dim3(256), 0, stream>>>(padj, pdist, bits);
  attn_k<<<dim3(16, NH, NB), dim3(256), 0, stream>>>(qb, kb, vtb, bits, gamma, ao);
  proj_gemm_k<<<dim3(8, 128), dim3(256), 0, stream>>>(ao, wpT, out);
}

// Round 9
// 287.787 us; speedup vs baseline: 1.0008x; 1.0008x over previous
//
#include <hip/hip_runtime.h>
#include <hip/hip_bf16.h>
#include <stdint.h>

// Problem constants
#define NB 8
#define NL 1024
#define NC 512
#define NH 8
#define ND 64

typedef __attribute__((ext_vector_type(8))) short short8;
typedef __attribute__((ext_vector_type(4))) short short4v;
typedef __attribute__((ext_vector_type(4))) float f32x4;
typedef unsigned long long u64;

__device__ __forceinline__ short f2bf(float f) {
  union { float f; uint32_t u; } v; v.f = f;
  uint32_t r = v.u + 0x7FFFu + ((v.u >> 16) & 1u);  // RNE
  return (short)(r >> 16);
}

#if __has_builtin(__builtin_amdgcn_exp2f)
#define EXP2(x) __builtin_amdgcn_exp2f(x)
#else
#define EXP2(x) exp2f(x)
#endif

#define MFMA16(a, b, c) __builtin_amdgcn_mfma_f32_16x16x32_bf16((a), (b), (c), 0, 0, 0)

// ---------------------------------------------------------------------------
// K0: pack adj_local rows (row 0 / col 0 zeroed per has_cls) AND dist>0 rows
// ---------------------------------------------------------------------------
__global__ __launch_bounds__(256) void pack_k(const float* __restrict__ adj,
                                              const float* __restrict__ dist,
                                              u64* __restrict__ padj,
                                              u64* __restrict__ pdist) {
  int row = blockIdx.x;             // b*NL + i
  int i = row & (NL - 1);
  int wv = threadIdx.x >> 6, lane = threadIdx.x & 63;
  const float* asrc = adj + (size_t)row * NL;
  const float* dsrc = dist + (size_t)row * NL;
  #pragma unroll
  for (int it = 0; it < 4; it++) {
    int j = wv * 256 + it * 64 + lane;
    float a = asrc[j];
    float d = dsrc[j];
    u64 am = __ballot((a != 0.0f) && (i != 0) && (j != 0));
    u64 dm = __ballot(d > 0.0f);
    if (lane == 0) {
      padj[(size_t)row * 16 + wv * 4 + it] = am;
      pdist[(size_t)row * 16 + wv * 4 + it] = dm;
    }
  }
}

// ---------------------------------------------------------------------------
// K2: 5-bit bias masks per (b,i,j) from packed bitmasks.
// ---------------------------------------------------------------------------
__global__ __launch_bounds__(256) void bits_k(const u64* __restrict__ padj,
                                              const u64* __restrict__ pdist,
                                              unsigned char* __restrict__ bits) {
  __shared__ u64 Pi[64][17], Pj[64][17];
  __shared__ u64 DiW[64], DjW[64];
  int b = blockIdx.z, i0 = blockIdx.y * 64, j0 = blockIdx.x * 64;
  int t = threadIdx.x;
  int jw = j0 >> 6, iw = i0 >> 6;
  const u64* pa = padj + (size_t)b * NL * 16;
  const u64* pd = pdist + (size_t)b * NL * 16;
  #pragma unroll
  for (int s = 0; s < 4; s++) {
    int idx = s * 256 + t; int r = idx >> 4, w = idx & 15;
    Pi[r][w] = pa[(size_t)(i0 + r) * 16 + w];
    Pj[r][w] = pa[(size_t)(j0 + r) * 16 + w];
  }
  if (t < 64) DiW[t] = pd[(size_t)(i0 + t) * 16 + jw];
  else if (t < 128) DjW[t - 64] = pd[(size_t)(j0 + t - 64) * 16 + iw];
  __syncthreads();
  const size_t base = (size_t)b * NL * NL;
  int jj0 = (t & 15) * 4;
  #pragma unroll
  for (int s = 0; s < 4; s++) {
    int ii = (t >> 4) + s * 16;
    u64 fwdw = Pi[ii][jw];
    u64 dfw = DiW[ii];
    uint32_t acc = 0;
    #pragma unroll
    for (int q = 0; q < 4; q++) {
      int jj = jj0 + q;
      unsigned v = 0;
      v |= (unsigned)((fwdw >> jj) & 1);
      v |= (unsigned)((Pj[jj][iw] >> ii) & 1) << 1;
      v |= (unsigned)((dfw >> jj) & 1) << 2;
      v |= (unsigned)((DjW[jj] >> ii) & 1) << 3;
      #pragma unroll 1
      for (int w = 0; w < 16; w++) {
        if (Pi[ii][w] & Pj[jj][w]) { v |= 16; break; }
      }
      acc |= v << (8 * q);
    }
    *(uint32_t*)&bits[base + (size_t)(i0 + ii) * NL + j0 + jj0] = acc;
  }
}

// ---------------------------------------------------------------------------
// K0b: convert+transpose a weight matrix: w[K][N] f32 -> wt[N][K] bf16.
// ---------------------------------------------------------------------------
__global__ __launch_bounds__(256) void wcvt_k(const float* __restrict__ w,
                                              unsigned short* __restrict__ wt,
                                              int Ndim) {
  __shared__ short T[64][68];
  int k0 = blockIdx.y * 64, n0 = blockIdx.x * 64;
  int t = threadIdx.x;
  {
    int r = t >> 2, c0 = (t & 3) * 16;
    const float* src = w + (size_t)(k0 + r) * Ndim + n0 + c0;
    float4 a0 = *(const float4*)src;
    float4 a1 = *(const float4*)(src + 4);
    float4 a2 = *(const float4*)(src + 8);
    float4 a3 = *(const float4*)(src + 12);
    short8 s0, s1;
    s0[0] = f2bf(a0.x); s0[1] = f2bf(a0.y); s0[2] = f2bf(a0.z); s0[3] = f2bf(a0.w);
    s0[4] = f2bf(a1.x); s0[5] = f2bf(a1.y); s0[6] = f2bf(a1.z); s0[7] = f2bf(a1.w);
    s1[0] = f2bf(a2.x); s1[1] = f2bf(a2.y); s1[2] = f2bf(a2.z); s1[3] = f2bf(a2.w);
    s1[4] = f2bf(a3.x); s1[5] = f2bf(a3.y); s1[6] = f2bf(a3.z); s1[7] = f2bf(a3.w);
    *(short8*)&T[r][c0]     = s0;
    *(short8*)&T[r][c0 + 8] = s1;
  }
  __syncthreads();
  #pragma unroll
  for (int it = 0; it < 2; it++) {
    int nn = (t >> 3) + it * 32, kc = (t & 7) * 8;
    short8 v;
    #pragma unroll
    for (int j = 0; j < 8; j++) v[j] = T[kc + j][nn];
    *(short8*)(wt + (size_t)(n0 + nn) * NC + k0 + kc) = v;
  }
}

// ---------------------------------------------------------------------------
// K0c: convert x [B*L][C] f32 -> bf16 (flat, vectorized)
// ---------------------------------------------------------------------------
__global__ __launch_bounds__(256) void xcvt_k(const float* __restrict__ x,
                                              unsigned short* __restrict__ xb) {
  size_t i = ((size_t)blockIdx.x * 256 + threadIdx.x) * 8;
  float4 a0 = *(const float4*)(x + i);
  float4 a1 = *(const float4*)(x + i + 4);
  short8 s;
  s[0] = f2bf(a0.x); s[1] = f2bf(a0.y); s[2] = f2bf(a0.z); s[3] = f2bf(a0.w);
  s[4] = f2bf(a1.x); s[5] = f2bf(a1.y); s[6] = f2bf(a1.z); s[7] = f2bf(a1.w);
  *(short8*)(xb + i) = s;
}

// ---------------------------------------------------------------------------
// K1: qkv = xb @ wqT^T  (128x128 tile, BK=32, 4 waves 2x2, wave = 64x64).
// Scatter to q/k/v [B,H,L,D] bf16; q pre-scaled by 0.125.
// ---------------------------------------------------------------------------
__global__ __launch_bounds__(256) void qkv_gemm_k(const unsigned short* __restrict__ xb,
                                                  const unsigned short* __restrict__ wqT,
                                                  unsigned short* __restrict__ qb,
                                                  unsigned short* __restrict__ kb,
                                                  unsigned short* __restrict__ vb) {
  __shared__ short Al[128][40];
  __shared__ short Bl[128][40];
  int t = threadIdx.x;
  int wv = t >> 6, lane = t & 63, lg = lane >> 4, lm = lane & 15;
  int wr = wv >> 1, wc = wv & 1;
  int M0 = blockIdx.y * 128, N0 = blockIdx.x * 128;
  f32x4 zero4 = {0.f, 0.f, 0.f, 0.f};
  f32x4 acc[4][4];
  #pragma unroll
  for (int mi = 0; mi < 4; mi++)
    #pragma unroll
    for (int ni = 0; ni < 4; ni++) acc[mi][ni] = zero4;
  int srow = t & 127, scc = (t >> 7) * 16;
  for (int k0 = 0; k0 < NC; k0 += 32) {
    const unsigned short* as = xb + (size_t)(M0 + srow) * NC + k0 + scc;
    *(short8*)&Al[srow][scc]     = *(const short8*)as;
    *(short8*)&Al[srow][scc + 8] = *(const short8*)(as + 8);
    const unsigned short* bs = wqT + (size_t)(N0 + srow) * NC + k0 + scc;
    *(short8*)&Bl[srow][scc]     = *(const short8*)bs;
    *(short8*)&Bl[srow][scc + 8] = *(const short8*)(bs + 8);
    __syncthreads();
    short8 af[4], bfr[4];
    #pragma unroll
    for (int mi = 0; mi < 4; mi++) af[mi] = *(short8*)&Al[wr * 64 + mi * 16 + lm][lg * 8];
    #pragma unroll
    for (int ni = 0; ni < 4; ni++) bfr[ni] = *(short8*)&Bl[wc * 64 + ni * 16 + lm][lg * 8];
    #pragma unroll
    for (int mi = 0; mi < 4; mi++)
      #pragma unroll
      for (int ni = 0; ni < 4; ni++)
        acc[mi][ni] = MFMA16(af[mi], bfr[ni], acc[mi][ni]);
    __syncthreads();
  }
  #pragma unroll
  for (int mi = 0; mi < 4; mi++)
    #pragma unroll
    for (int ni = 0; ni < 4; ni++)
      #pragma unroll
      for (int r = 0; r < 4; r++) {
        int m = M0 + wr * 64 + mi * 16 + lg * 4 + r;
        int n = N0 + wc * 64 + ni * 16 + lm;
        int which = n >> 9, c = n & 511;
        int h = c >> 6, d = c & 63;
        int bb = m >> 10, ll = m & 1023;
        float val = acc[mi][ni][r];
        unsigned short* dst;
        if (which == 0) { dst = qb; val *= 0.125f; }
        else dst = (which == 1) ? kb : vb;
        dst[(((size_t)bb * NH + h) * NL + ll) * ND + d] = (unsigned short)f2bf(val);
      }
}

// ---------------------------------------------------------------------------
// K1b: transpose V [B,H,L,D] -> [B,H,D,L]
// ---------------------------------------------------------------------------
__global__ __launch_bounds__(256) void vt_k(const unsigned short* __restrict__ vb,
                                            unsigned short* __restrict__ vtb) {
  __shared__ short T[64][68];
  int b = blockIdx.z, h = blockIdx.y, l0 = blockIdx.x * 64;
  int t = threadIdx.x;
  const size_t bh = (size_t)b * NH + h;
  {
    int r = t >> 2, c0 = (t & 3) * 16;
    const unsigned short* src = vb + ((bh * NL) + l0 + r) * ND + c0;
    *(short8*)&T[r][c0]     = *(const short8*)src;
    *(short8*)&T[r][c0 + 8] = *(const short8*)(src + 8);
  }
  __syncthreads();
  #pragma unroll
  for (int it = 0; it < 2; it++) {
    int d = (t >> 3) + it * 32, lc = (t & 7) * 8;
    short8 v;
    #pragma unroll
    for (int j = 0; j < 8; j++) v[j] = T[lc + j][d];
    *(short8*)(vtb + (bh * ND + d) * NL + l0 + lc) = v;
  }
}

// ---------------------------------------------------------------------------
// K3: fused flash attention, fixed-shift exp2 softmax, SWAPPED operands.
// 2 waves x 32 q-rows; S^T = mfma(K, Q) puts consecutive kv in-lane:
//  - bits: 1 dword load per (mi,ni)         (was 4 byte loads)
//  - P: packed dword LDS writes, 2-way-free (was scalar b16, the 4.19e6 confl.)
//  - PV^T = mfma(V^T, P): same V/P fragment reads as before
//  - lsum: 1 scalar per mi + 2 shfls at end; ao: packed short4 stores
// ---------------------------------------------------------------------------
__global__ __launch_bounds__(128) void attn_k(const unsigned short* __restrict__ qb,
                                              const unsigned short* __restrict__ kb,
                                              const unsigned short* __restrict__ vtb,
                                              const unsigned char* __restrict__ bits,
                                              const float* __restrict__ gamma,
                                              unsigned short* __restrict__ ao) {
  __shared__ short Kl[64][72];   // [kv][d]
  __shared__ short Vt[64][72];   // [d][kv]
  __shared__ short Pl[64][72];   // [q][kv] bf16 probs
  __shared__ float lut[32];
  int b = blockIdx.z, h = blockIdx.y, q0 = blockIdx.x * 64;
  int t = threadIdx.x, wv = t >> 6, lane = t & 63, lg = lane >> 4, lm = lane & 15;
  const float LOG2E = 1.4426950408889634f;
  if (t < 32) {
    float s = 0.f;
    #pragma unroll
    for (int k = 0; k < 5; k++) if ((t >> k) & 1) s += gamma[h * 5 + k];
    lut[t] = s * LOG2E - 8.0f;   // exp2-domain bias + fixed shift
  }
  const size_t bh = ((size_t)b * NH + h) * NL;
  const size_t bhD = ((size_t)b * NH + h) * ND;
  short8 qf[2][2];
  #pragma unroll
  for (int mi = 0; mi < 2; mi++) {
    const unsigned short* src = qb + (bh + q0 + wv * 32 + mi * 16 + lm) * ND + lg * 8;
    qf[mi][0] = *(const short8*)src;
    qf[mi][1] = *(const short8*)(src + 32);
  }
  f32x4 zero4 = {0.f, 0.f, 0.f, 0.f};
  f32x4 oaccT[4][2];             // [di][mi]: D2[d][q]
  #pragma unroll
  for (int di = 0; di < 4; di++) { oaccT[di][0] = zero4; oaccT[di][1] = zero4; }
  float lsum[2] = {0.f, 0.f};
  int sr = t >> 1, sc = (t & 1) * 32;
  const unsigned short* krow = kb + (bh + sr) * ND + sc;
  const unsigned short* vrow = vtb + (bhD + sr) * NL + sc;
  __syncthreads();
  for (int ti = 0; ti < 16; ti++) {
    int j0 = ti * 64;
    {
      const unsigned short* ks = krow + (size_t)j0 * ND;
      *(short8*)&Kl[sr][sc]      = *(const short8*)ks;
      *(short8*)&Kl[sr][sc + 8]  = *(const short8*)(ks + 8);
      *(short8*)&Kl[sr][sc + 16] = *(const short8*)(ks + 16);
      *(short8*)&Kl[sr][sc + 24] = *(const short8*)(ks + 24);
      const unsigned short* vs = vrow + j0;
      *(short8*)&Vt[sr][sc]      = *(const short8*)vs;
      *(short8*)&Vt[sr][sc + 8]  = *(const short8*)(vs + 8);
      *(short8*)&Vt[sr][sc + 16] = *(const short8*)(vs + 16);
      *(short8*)&Vt[sr][sc + 24] = *(const short8*)(vs + 24);
    }
    __syncthreads();
    // S^T = K Q^T: lane holds (kv = ni*16+4lg+r, q = wv*32+mi*16+lm)
    f32x4 sfT[2][4];
    #pragma unroll
    for (int ni = 0; ni < 4; ni++) {
      short8 kf0 = *(short8*)&Kl[ni * 16 + lm][lg * 8];
      short8 kf1 = *(short8*)&Kl[ni * 16 + lm][32 + lg * 8];
      #pragma unroll
      for (int mi = 0; mi < 2; mi++) {
        f32x4 c = {0.f, 0.f, 0.f, 0.f};
        c = MFMA16(kf0, qf[mi][0], c);
        c = MFMA16(kf1, qf[mi][1], c);
        sfT[mi][ni] = c;
      }
    }
    // softmax (fixed shift) + pack kv-pairs to dwords + P store
    #pragma unroll
    for (int mi = 0; mi < 2; mi++) {
      int qrow = q0 + wv * 32 + mi * 16 + lm;
      const unsigned char* bp = bits + ((size_t)b * NL + qrow) * NL + j0 + 4 * lg;
      int prow = wv * 32 + mi * 16 + lm;
      #pragma unroll
      for (int ni = 0; ni < 4; ni++) {
        uint32_t bw = *(const uint32_t*)(bp + ni * 16);
        float p0 = EXP2(fmaf(sfT[mi][ni][0], LOG2E, lut[bw & 31]));
        float p1 = EXP2(fmaf(sfT[mi][ni][1], LOG2E, lut[(bw >> 8) & 31]));
        float p2 = EXP2(fmaf(sfT[mi][ni][2], LOG2E, lut[(bw >> 16) & 31]));
        float p3 = EXP2(fmaf(sfT[mi][ni][3], LOG2E, lut[(bw >> 24) & 31]));
        lsum[mi] += (p0 + p1) + (p2 + p3);
        uint32_t d0 = (uint32_t)(unsigned short)f2bf(p0) |
                      ((uint32_t)(unsigned short)f2bf(p1) << 16);
        uint32_t d1 = (uint32_t)(unsigned short)f2bf(p2) |
                      ((uint32_t)(unsigned short)f2bf(p3) << 16);
        *(uint32_t*)&Pl[prow][ni * 16 + 4 * lg]     = d0;
        *(uint32_t*)&Pl[prow][ni * 16 + 4 * lg + 2] = d1;
      }
    }
    // PV^T = V^T P : A = Vt-frag, B = P-frag (wave-private rows, no barrier)
    short8 pf[2][2];
    #pragma unroll
    for (int mi = 0; mi < 2; mi++) {
      pf[mi][0] = *(short8*)&Pl[wv * 32 + mi * 16 + lm][lg * 8];
      pf[mi][1] = *(short8*)&Pl[wv * 32 + mi * 16 + lm][32 + lg * 8];
    }
    #pragma unroll
    for (int di = 0; di < 4; di++) {
      short8 vf0 = *(short8*)&Vt[di * 16 + lm][lg * 8];
      short8 vf1 = *(short8*)&Vt[di * 16 + lm][32 + lg * 8];
      #pragma unroll
      for (int mi = 0; mi < 2; mi++) {
        oaccT[di][mi] = MFMA16(vf0, pf[mi][0], oaccT[di][mi]);
        oaccT[di][mi] = MFMA16(vf1, pf[mi][1], oaccT[di][mi]);
      }
    }
    __syncthreads();
  }
  // final row-sum reduce across the 4 lanes sharing lm (lg groups)
  float inv[2];
  #pragma unroll
  for (int mi = 0; mi < 2; mi++) {
    float s = lsum[mi];
    s += __shfl_xor(s, 16);
    s += __shfl_xor(s, 32);
    inv[mi] = 1.0f / s;
  }
  // packed stores: lane writes 4 consecutive d per (di,mi)
  #pragma unroll
  for (int di = 0; di < 4; di++)
    #pragma unroll
    for (int mi = 0; mi < 2; mi++) {
      int qi = q0 + wv * 32 + mi * 16 + lm;
      short4v o;
      #pragma unroll
      for (int r = 0; r < 4; r++) o[r] = f2bf(oaccT[di][mi][r] * inv[mi]);
      *(short4v*)(ao + ((size_t)b * NL + qi) * NC + h * ND + di * 16 + 4 * lg) = o;
    }
}

// ---------------------------------------------------------------------------
// K4: out = attn_out @ w_proj  (bf16 MFMA, f32 out)
// ---------------------------------------------------------------------------
__global__ __launch_bounds__(256) void proj_gemm_k(const unsigned short* __restrict__ ao,
                                                   const unsigned short* __restrict__ wpT,
                                                   float* __restrict__ out) {
  __shared__ short Al[64][40];
  __shared__ short Bl[64][40];
  int t = threadIdx.x;
  int wv = t >> 6, lane = t & 63, lg = lane >> 4, lm = lane & 15;
  int wr = wv >> 1, wc = wv & 1;
  int M0 = blockIdx.y * 64, N0 = blockIdx.x * 64;
  f32x4 zero4 = {0.f, 0.f, 0.f, 0.f};
  f32x4 acc[2][2] = {{zero4, zero4}, {zero4, zero4}};
  for (int k0 = 0; k0 < NC; k0 += 32) {
    {
      int row = t >> 2, cc = (t & 3) * 8;
      *(short8*)&Al[row][cc] = *(const short8*)(ao + (size_t)(M0 + row) * NC + k0 + cc);
    }
    {
      int n = t >> 2, kk = (t & 3) * 8;
      *(short8*)&Bl[n][kk] =
          *(const short8*)(wpT + (size_t)(N0 + n) * NC + k0 + kk);
    }
    __syncthreads();
    short8 af[2], bfr[2];
    af[0] = *(short8*)&Al[wr * 32 + lm][lg * 8];
    af[1] = *(short8*)&Al[wr * 32 + 16 + lm][lg * 8];
    bfr[0] = *(short8*)&Bl[wc * 32 + lm][lg * 8];
    bfr[1] = *(short8*)&Bl[wc * 32 + 16 + lm][lg * 8];
    #pragma unroll
    for (int mi = 0; mi < 2; mi++)
      #pragma unroll
      for (int ni = 0; ni < 2; ni++)
        acc[mi][ni] = MFMA16(af[mi], bfr[ni], acc[mi][ni]);
    __syncthreads();
  }
  #pragma unroll
  for (int mi = 0; mi < 2; mi++)
    #pragma unroll
    for (int ni = 0; ni < 2; ni++)
      #pragma unroll
      for (int r = 0; r < 4; r++) {
        int m = M0 + wr * 32 + mi * 16 + lg * 4 + r;
        int n = N0 + wc * 32 + ni * 16 + lm;
        out[(size_t)m * NC + n] = acc[mi][ni][r];
      }
}

// ---------------------------------------------------------------------------
extern "C" void kernel_launch(void* const* d_in, const int* in_sizes, int n_in,
                              void* d_out, int out_size, void* d_ws, size_t ws_size,
                              hipStream_t stream) {
  (void)in_sizes; (void)n_in; (void)out_size; (void)ws_size;
  const float* x      = (const float*)d_in[0];
  const float* adj    = (const float*)d_in[1];
  const float* dist   = (const float*)d_in[2];
  const float* w_qkv  = (const float*)d_in[3];
  const float* w_proj = (const float*)d_in[4];
  const float* gamma  = (const float*)d_in[5];
  float* out = (float*)d_out;

  // workspace layout (~55 MB; ao aliases xb — xb dead after qkv_gemm)
  char* ws = (char*)d_ws;
  size_t off = 0;
  auto take = [&](size_t bytes) -> char* {
    char* p = ws + off;
    off += (bytes + 255) & ~(size_t)255;
    return p;
  };
  unsigned short* qb = (unsigned short*)take((size_t)NB * NH * NL * ND * 2);
  unsigned short* kb = (unsigned short*)take((size_t)NB * NH * NL * ND * 2);
  unsigned short* vb = (unsigned short*)take((size_t)NB * NH * NL * ND * 2);
  unsigned short* vtb = (unsigned short*)take((size_t)NB * NH * NL * ND * 2);
  u64* padj  = (u64*)take((size_t)NB * NL * 16 * 8);
  u64* pdist = (u64*)take((size_t)NB * NL * 16 * 8);
  unsigned char* bits = (unsigned char*)take((size_t)NB * NL * NL);
  unsigned short* xb = (unsigned short*)take((size_t)NB * NL * NC * 2);
  unsigned short* ao = xb;   // alias: attn writes ao after qkv_gemm consumed xb
  unsigned short* wqT = (unsigned short*)take((size_t)3 * NC * NC * 2);
  unsigned short* wpT = (unsigned short*)take((size_t)NC * NC * 2);

  pack_k<<<dim3(NB * NL), dim3(256), 0, stream>>>(adj, dist, padj, pdist);
  wcvt_k<<<dim3(24, 8), dim3(256), 0, stream>>>(w_qkv, wqT, 3 * NC);
  wcvt_k<<<dim3(8, 8), dim3(256), 0, stream>>>(w_proj, wpT, NC);
  xcvt_k<<<dim3((NB * NL * NC) / (256 * 8)), dim3(256), 0, stream>>>(x, xb);
  qkv_gemm_k<<<dim3(12, 64), dim3(256), 0, stream>>>(xb, wqT, qb, kb, vb);
  vt_k<<<dim3(16, NH, NB), dim3(256), 0, stream>>>(vb, vtb);
  bits_k<<<dim3(16, 16, NB), dim3(256), 0, stream>>>(padj, pdist, bits);
  attn_k<<<dim3(16, NH, NB), dim3(128), 0, stream>>>(qb, kb, vtb, bits, gamma, ao);
  proj_gemm_k<<<dim3(8, 128), dim3(256), 0, stream>>>(ao, wpT, out);
}